// Round 8
// baseline (305.899 us; speedup 1.0000x reference)
//
#include <hip/hip_runtime.h>
#include <stdint.h>

#define Bc 32768
#define NSTAG 2048383
#define NFULL 2097152
#define P_TOTAL (17*Bc)   // 557056 = 4352 * 128

typedef short  short8_t __attribute__((ext_vector_type(8)));
typedef __bf16 bf16x8_t __attribute__((ext_vector_type(8)));
typedef float  f32x4_t  __attribute__((ext_vector_type(4)));

#if __has_builtin(__builtin_amdgcn_exp2f)
#define EXP2F(x) __builtin_amdgcn_exp2f(x)
#else
#define EXP2F(x) exp2f(x)
#endif
#if __has_builtin(__builtin_amdgcn_rcpf)
#define RCPF(x) __builtin_amdgcn_rcpf(x)
#else
#define RCPF(x) (1.0f/(x))
#endif

// tanh(x) = 1 - 2/(e^{2x}+1); e^{2x} = 2^(x*2*log2 e). 5 insts, exact at +-inf.
__device__ __forceinline__ float fast_tanh(float x){
  float e = EXP2F(x * 2.885390081777927f);
  return fmaf(-2.0f, RCPF(e + 1.0f), 1.0f);
}

__device__ __forceinline__ short f2bf(float f){
  union { float f; unsigned u; } v; v.f = f;
  unsigned r = v.u + 0x7FFFu + ((v.u >> 16) & 1u);   // RNE
  return (short)(r >> 16);
}

// ---- weight transpose + bf16 convert: W2t[j][k] = bf16(W2[k][j]), same for W3
__global__ void lap_convert_w(const float* __restrict__ W2, const float* __restrict__ W3,
                              short* __restrict__ W2t, short* __restrict__ W3t){
  int o = blockIdx.x * 256 + threadIdx.x;      // 0..32767
  int which = o >> 14; int e = o & 16383;
  int j = e >> 7, k = e & 127;
  const float* W = which ? W3 : W2;
  short* O = which ? W3t : W2t;
  O[e] = f2bf(W[k*128 + j]);
}

// ---- main MLP kernel: 128 points per block, 32 per wave, fully wave-private.
// gfx950 unified-RF model (r1-r7): MFMA operands/accs get an AGPR carve-out;
// under cap = 512/min_waves the arch side gets cap-minus-AGPR. r7: AGPR 64
// (afr[8]+acc[2][4]) left arch=64 < demand 88 -> spill. This version halves the
// MFMA footprint (rt-split: afr[4]+acc[4], AGPR ~32) so arch cap 96 >= ~75.
__global__ __launch_bounds__(256, 4)
void lap_mlp_kernel(const float* __restrict__ DATAX, const float* __restrict__ STAGX,
                    const int* __restrict__ cidx,
                    const float* __restrict__ W1, const float* __restrict__ b1,
                    const float* __restrict__ b2, const float* __restrict__ b3,
                    const float* __restrict__ W4, const float* __restrict__ b4,
                    const short* __restrict__ W2t, const short* __restrict__ W3t,
                    float* __restrict__ out)
{
  __shared__ short lds_h[128*128];   // 32 KB activations; rows XOR-swizzled (256B stride)
  const int t    = threadIdx.x;
  const int lane = t & 63;
  const int wv   = t >> 6;
  const int rbase = wv * 32;                    // this wave's private 32 rows
  const int pbase = blockIdx.x * 128 + rbase;   // this wave's 32 points
  const int l31 = lane & 31;

  // ---- gather: each lane loads coords for row (lane&31); 2 lanes/row redundant (L1-merged)
  float x0, x1, x2;
  {
    int p = pbase + l31;
    const float* sp;
    if (p < Bc) {
      sp = DATAX + 3*(size_t)cidx[p];
    } else {
      int q = p - Bc;
      int isNeig = (q >= 8*Bc) ? 1 : 0;
      if (isNeig) q -= 8*Bc;
      int b = q >> 3, s5 = q & 7;
      int i = cidx[b];
      int ix = i >> 14, iy = (i >> 7) & 127, iz = i & 127;
      int bx = (s5 >> 2) & 1, by = (s5 >> 1) & 1, bz = s5 & 1;
      int dx, dy, dz, hi;
      if (isNeig) { dx = 2*bx-1; dy = 2*by-1; dz = 2*bz-1; hi = NFULL-1; }
      else        { dx = bx-1;   dy = by-1;   dz = bz-1;   hi = NSTAG-1; }
      // reference uses reduced-grid strides (127*127, 127) for BOTH gathers
      int f = (ix+dx)*16129 + (iy+dy)*127 + (iz+dz);
      f = f < 0 ? 0 : (f > hi ? hi : f);
      sp = (isNeig ? DATAX : STAGX) + 3*(size_t)f;
    }
    x0 = sp[0]; x1 = sp[1]; x2 = sp[2];
  }

  // ---- layer 1 (VALU): h1 = tanh(x @ W1 + b1); lane handles row (lane&31), j-half (lane>>5)
  {
    int m = rbase + l31;
    int jh = lane >> 5;
    int swz = (m & 7) << 4;
    char* rowp = (char*)lds_h + m*256;
    const f32x4_t* W1v = (const f32x4_t*)W1;   // [3][32] of float4
    const f32x4_t* b1v = (const f32x4_t*)b1;
    #pragma unroll
    for (int c8 = 0; c8 < 8; ++c8) {
      int j0 = jh*64 + c8*8;
      int q = j0 >> 2;
      f32x4_t bb[2] = { b1v[q],    b1v[q+1] };
      f32x4_t w0[2] = { W1v[q],    W1v[q+1] };
      f32x4_t w1[2] = { W1v[32+q], W1v[32+q+1] };
      f32x4_t w2[2] = { W1v[64+q], W1v[64+q+1] };
      bf16x8_t hv;
      #pragma unroll
      for (int u = 0; u < 8; ++u) {
        int h4 = u >> 2, e4 = u & 3;
        float a = bb[h4][e4] + x0*w0[h4][e4] + x1*w1[h4][e4] + x2*w2[h4][e4];
        hv[u] = (__bf16)fast_tanh(a);
      }
      *(bf16x8_t*)(rowp + ((j0*2) ^ swz)) = hv;   // b128 write
    }
  }
  // no barrier: per-wave DS ops are processed in order; reads below see this wave's writes

  // ---- layers 2,3 (MFMA); B-fragments straight from global (L1/L2-resident 32KB weights)
  const int lrow = lane & 15, lk = lane >> 4;
  auto gemm_layer = [&](const short* __restrict__ Wt, const float* __restrict__ bias){
    const short* wp = Wt + lrow*128 + lk*8;       // row j=ct*16+lrow, k=kk*32+lk*8
    // rt-split: one 16-row tile at a time -> afr[4](16) + acc[4](16) + b(32) live
    #pragma unroll
    for (int rt = 0; rt < 2; ++rt) {
      const int rr = rbase + rt*16 + lrow;
      const int swzr = (rr & 7) << 4;
      bf16x8_t afr[4];
      #pragma unroll
      for (int kk = 0; kk < 4; ++kk)
        afr[kk] = *(const bf16x8_t*)((char*)lds_h + rr*256 + ((kk*64 + lk*16) ^ swzr));
      #pragma unroll
      for (int half = 0; half < 2; ++half) {
        f32x4_t acc[4];
        #pragma unroll
        for (int c = 0; c < 4; ++c) acc[c] = (f32x4_t){0.f,0.f,0.f,0.f};
        bf16x8_t bcur[4], bnext[4];
        #pragma unroll
        for (int c = 0; c < 4; ++c)
          bcur[c] = *(const bf16x8_t*)(wp + (half*4 + c)*2048);
        #pragma unroll
        for (int kk = 0; kk < 4; ++kk) {
          if (kk < 3) {
            #pragma unroll
            for (int c = 0; c < 4; ++c)
              bnext[c] = *(const bf16x8_t*)(wp + (half*4 + c)*2048 + (kk+1)*32);
          }
          #pragma unroll
          for (int c = 0; c < 4; ++c)
            acc[c] = __builtin_amdgcn_mfma_f32_16x16x32_bf16(afr[kk], bcur[c], acc[c], 0, 0, 0);
          __builtin_amdgcn_sched_barrier(0);   // fence: no load hoisting past this kk-step
          #pragma unroll
          for (int c = 0; c < 4; ++c) bcur[c] = bnext[c];   // register rename
        }
        // epilogue: bias + tanh -> bf16 into rows [rbase+rt*16, +16) (afr snapshot in regs)
        #pragma unroll
        for (int c = 0; c < 4; ++c) {
          int j = (half*4 + c)*16 + lrow;
          float bj = bias[j];
          #pragma unroll
          for (int u = 0; u < 4; ++u) {
            int r = rbase + rt*16 + lk*4 + u;   // D layout: col=lane&15, row=(lane>>4)*4+u
            float v = fast_tanh(acc[c][u] + bj);
            *(__bf16*)((char*)lds_h + r*256 + ((j*2) ^ ((r & 7) << 4))) = (__bf16)v;
          }
        }
        __builtin_amdgcn_sched_barrier(0);   // fence: next phase's loads stay below
      }
    }
  };
  gemm_layer(W2t, b2);
  gemm_layer(W3t, b3);

  // ---- layer 4 (VALU): out = h3 @ W4 + b4; lane does row (lane&31), k-half (lane>>5)
  {
    int m = rbase + l31;
    int kh = lane >> 5;
    int swz = (m & 7) << 4;
    const f32x4_t* W4v = (const f32x4_t*)W4;
    float acc = 0.f;
    #pragma unroll
    for (int c = 0; c < 8; ++c) {
      int kb = kh*128 + c*16;
      bf16x8_t v = *(const bf16x8_t*)((char*)lds_h + m*256 + (kb ^ swz));
      f32x4_t wa = W4v[kh*16 + c*2], wb = W4v[kh*16 + c*2 + 1];
      #pragma unroll
      for (int u = 0; u < 4; ++u) acc += (float)v[u] * wa[u];
      #pragma unroll
      for (int u = 0; u < 4; ++u) acc += (float)v[4+u] * wb[u];
    }
    acc += __shfl_xor(acc, 32);    // combine the two k-halves (same m)
    if (lane < 32) out[pbase + l31] = acc + b4[0];
  }
}

// ---- per-center loss terms + deterministic block partials (no atomics)
__global__ __launch_bounds__(256)
void lap_reduce_kernel(const int* __restrict__ cidx, const float* __restrict__ DATAF,
                       const float* __restrict__ LAPLF, const float* __restrict__ mlp,
                       float* __restrict__ partials)
{
  int b = blockIdx.x * 256 + threadIdx.x;   // exactly Bc threads
  int i = cidx[b];
  int ix = i >> 14, iy = (i >> 7) & 127, iz = i & 127;
  bool interior = (ix >= 1) && (ix < 127) && (iy >= 1) && (iy < 127) && (iz >= 1) && (iz < 127);
  float e = fabsf(mlp[b] - DATAF[i]);
  const f32x4_t* ps4 = (const f32x4_t*)(mlp + Bc   + 8*(size_t)b);
  const f32x4_t* pn4 = (const f32x4_t*)(mlp + 9*Bc + 8*(size_t)b);
  f32x4_t psa = ps4[0], psb = ps4[1], pna = pn4[0], pnb = pn4[1];
  auto term = [](float a, float bq, float c, float d){
    return fabsf(a + bq - c - d) / ((a + bq + c + d) * 1.5f);
  };
  float lap = term(pnb[3], pna[0], psb[3], psa[0])    // pn7,pn0,ps7,ps0
            + term(pna[3], pnb[0], psa[3], psb[0])    // pn3,pn4,ps3,ps4
            + term(pnb[1], pna[2], psb[1], psa[2]);   // pn5,pn2,ps5,ps2
  float dl = LAPLF[i] - lap;
  float sq = interior ? dl*dl : 0.f;
  float cn = interior ? 1.f : 0.f;
  #pragma unroll
  for (int o = 32; o > 0; o >>= 1) {
    e  += __shfl_down(e, o);
    sq += __shfl_down(sq, o);
    cn += __shfl_down(cn, o);
  }
  __shared__ float sm[4][3];
  int w = threadIdx.x >> 6;
  if ((threadIdx.x & 63) == 0) { sm[w][0]=e; sm[w][1]=sq; sm[w][2]=cn; }
  __syncthreads();
  if (threadIdx.x == 0) {
    float se=0, ss=0, sc=0;
    #pragma unroll
    for (int k = 0; k < 4; ++k){ se+=sm[k][0]; ss+=sm[k][1]; sc+=sm[k][2]; }
    partials[blockIdx.x*4+0]=se; partials[blockIdx.x*4+1]=ss; partials[blockIdx.x*4+2]=sc;
  }
}

__global__ void lap_finalize_kernel(const float* __restrict__ partials, float* __restrict__ out){
  int l = threadIdx.x;   // 64 threads
  float se=0, ss=0, sc=0;
  for (int r = l; r < 128; r += 64) {
    se += partials[4*r+0]; ss += partials[4*r+1]; sc += partials[4*r+2];
  }
  #pragma unroll
  for (int o = 32; o > 0; o >>= 1) {
    se += __shfl_down(se, o); ss += __shfl_down(ss, o); sc += __shfl_down(sc, o);
  }
  if (l == 0) out[0] = se * (1.0f/32768.f) + ss / fmaxf(sc, 1.f);
}

extern "C" void kernel_launch(void* const* d_in, const int* in_sizes, int n_in,
                              void* d_out, int out_size, void* d_ws, size_t ws_size,
                              hipStream_t stream)
{
  const float* DATAX = (const float*)d_in[0];
  const float* DATAF = (const float*)d_in[1];
  const float* STAGX = (const float*)d_in[2];
  const float* LAPLF = (const float*)d_in[3];
  const float* W1    = (const float*)d_in[4];
  const float* b1    = (const float*)d_in[5];
  const float* W2    = (const float*)d_in[6];
  const float* b2    = (const float*)d_in[7];
  const float* W3    = (const float*)d_in[8];
  const float* b3    = (const float*)d_in[9];
  const float* W4    = (const float*)d_in[10];
  const float* b4    = (const float*)d_in[11];
  const int*   cidx  = (const int*)d_in[12];
  float* out = (float*)d_out;

  char* ws = (char*)d_ws;
  float* partials = (float*)ws;                 // 128*4 floats
  short* W2t      = (short*)(ws + 4096);        // 32 KB
  short* W3t      = (short*)(ws + 36864);       // 32 KB
  float* mlp_out  = (float*)(ws + 69632);       // 557056 floats (~2.2 MB)

  lap_convert_w<<<128, 256, 0, stream>>>(W2, W3, W2t, W3t);
  lap_mlp_kernel<<<P_TOTAL/128, 256, 0, stream>>>(DATAX, STAGX, cidx,
                                                  W1, b1, b2, b3, W4, b4,
                                                  W2t, W3t, mlp_out);
  lap_reduce_kernel<<<Bc/256, 256, 0, stream>>>(cidx, DATAF, LAPLF, mlp_out, partials);
  lap_finalize_kernel<<<1, 64, 0, stream>>>(partials, out);
}

// Round 9
// 115.197 us; speedup vs baseline: 2.6554x; 2.6554x over previous
//
#include <hip/hip_runtime.h>
#include <stdint.h>

#define Bc 32768
#define NSTAG 2048383
#define NFULL 2097152
#define P_TOTAL (17*Bc)   // 557056 = 4352 * 128

typedef short  short8_t __attribute__((ext_vector_type(8)));
typedef __bf16 bf16x8_t __attribute__((ext_vector_type(8)));
typedef float  f32x4_t  __attribute__((ext_vector_type(4)));

#if __has_builtin(__builtin_amdgcn_exp2f)
#define EXP2F(x) __builtin_amdgcn_exp2f(x)
#else
#define EXP2F(x) exp2f(x)
#endif
#if __has_builtin(__builtin_amdgcn_rcpf)
#define RCPF(x) __builtin_amdgcn_rcpf(x)
#else
#define RCPF(x) (1.0f/(x))
#endif

// tanh(x) = 1 - 2/(e^{2x}+1); e^{2x} = 2^(x*2*log2 e). 5 insts, exact at +-inf.
__device__ __forceinline__ float fast_tanh(float x){
  float e = EXP2F(x * 2.885390081777927f);
  return fmaf(-2.0f, RCPF(e + 1.0f), 1.0f);
}

__device__ __forceinline__ short f2bf(float f){
  union { float f; unsigned u; } v; v.f = f;
  unsigned r = v.u + 0x7FFFu + ((v.u >> 16) & 1u);   // RNE
  return (short)(r >> 16);
}

// ---- weight convert to FRAGMENT-MAJOR bf16 layout:
// Wf[((kk*8+ct)*64 + lane)*8 + u] = bf16(W[k][j]),  j = ct*16+(lane&15),
// k = kk*32+(lane>>4)*8+u.  B-loads become base + lane*16B + small imm.
__global__ void lap_convert_w(const float* __restrict__ W2, const float* __restrict__ W3,
                              short* __restrict__ W2f, short* __restrict__ W3f){
  int o = blockIdx.x * 256 + threadIdx.x;      // 0..32767
  int which = o >> 14; int e = o & 16383;
  int u = e & 7, lane = (e >> 3) & 63, ct = (e >> 9) & 7, kk = e >> 12;
  int j = ct*16 + (lane & 15);
  int k = kk*32 + (lane >> 4)*8 + u;
  const float* W = which ? W3 : W2;
  short* O = which ? W3f : W2f;
  O[e] = f2bf(W[k*128 + j]);
}

// ---- main MLP kernel: 128 points per block, 32 per wave, fully wave-private.
// Register model (r1-r8): MFMA operands (A+B+acc) go to the AGPR partition;
// arch gets cap-minus-AGPR. This version: AGPR = afr32+b16+acc16 = 64, arch
// demand cut by fragment-major W (1 addr base, not 8) -> fits (256,4) cap 128.
__global__ __launch_bounds__(256, 4)
void lap_mlp_kernel(const float* __restrict__ DATAX, const float* __restrict__ STAGX,
                    const int* __restrict__ cidx,
                    const float* __restrict__ W1, const float* __restrict__ b1,
                    const float* __restrict__ b2, const float* __restrict__ b3,
                    const float* __restrict__ W4, const float* __restrict__ b4,
                    const short* __restrict__ W2f, const short* __restrict__ W3f,
                    float* __restrict__ out)
{
  __shared__ short lds_h[128*128];   // 32 KB activations; rows XOR-swizzled (256B stride)
  const int t    = threadIdx.x;
  const int lane = t & 63;
  const int wv   = t >> 6;
  const int rbase = wv * 32;                    // this wave's private 32 rows
  const int pbase = blockIdx.x * 128 + rbase;   // this wave's 32 points
  const int l31 = lane & 31;

  // ---- gather: each lane loads coords for row (lane&31); 2 lanes/row redundant (L1-merged)
  float x0, x1, x2;
  {
    int p = pbase + l31;
    const float* sp;
    if (p < Bc) {
      sp = DATAX + 3*(size_t)cidx[p];
    } else {
      int q = p - Bc;
      int isNeig = (q >= 8*Bc) ? 1 : 0;
      if (isNeig) q -= 8*Bc;
      int b = q >> 3, s5 = q & 7;
      int i = cidx[b];
      int ix = i >> 14, iy = (i >> 7) & 127, iz = i & 127;
      int bx = (s5 >> 2) & 1, by = (s5 >> 1) & 1, bz = s5 & 1;
      int dx, dy, dz, hi;
      if (isNeig) { dx = 2*bx-1; dy = 2*by-1; dz = 2*bz-1; hi = NFULL-1; }
      else        { dx = bx-1;   dy = by-1;   dz = bz-1;   hi = NSTAG-1; }
      // reference uses reduced-grid strides (127*127, 127) for BOTH gathers
      int f = (ix+dx)*16129 + (iy+dy)*127 + (iz+dz);
      f = f < 0 ? 0 : (f > hi ? hi : f);
      sp = (isNeig ? DATAX : STAGX) + 3*(size_t)f;
    }
    x0 = sp[0]; x1 = sp[1]; x2 = sp[2];
  }

  // ---- layer 1 (VALU): h1 = tanh(x @ W1 + b1); lane handles row (lane&31), j-half (lane>>5)
  {
    int m = rbase + l31;
    int jh = lane >> 5;
    int swz = (m & 7) << 4;
    char* rowp = (char*)lds_h + m*256;
    const f32x4_t* W1v = (const f32x4_t*)W1;   // [3][32] of float4
    const f32x4_t* b1v = (const f32x4_t*)b1;
    #pragma unroll
    for (int c8 = 0; c8 < 8; ++c8) {
      int j0 = jh*64 + c8*8;
      int q = j0 >> 2;
      f32x4_t bb[2] = { b1v[q],    b1v[q+1] };
      f32x4_t w0[2] = { W1v[q],    W1v[q+1] };
      f32x4_t w1[2] = { W1v[32+q], W1v[32+q+1] };
      f32x4_t w2[2] = { W1v[64+q], W1v[64+q+1] };
      bf16x8_t hv;
      #pragma unroll
      for (int u = 0; u < 8; ++u) {
        int h4 = u >> 2, e4 = u & 3;
        float a = bb[h4][e4] + x0*w0[h4][e4] + x1*w1[h4][e4] + x2*w2[h4][e4];
        hv[u] = (__bf16)fast_tanh(a);
      }
      *(bf16x8_t*)(rowp + ((j0*2) ^ swz)) = hv;   // b128 write
    }
  }
  // no barrier: per-wave DS ops are processed in order; reads below see this wave's writes

  // ---- layers 2,3 (MFMA); B-fragments from global, fragment-major (L1-resident 32KB)
  const int lrow = lane & 15, lk = lane >> 4;
  const int r0 = rbase + lrow, r1 = r0 + 16;
  const int swz0 = (r0 & 7) << 4, swz1 = (r1 & 7) << 4;
  auto gemm_layer = [&](const short* __restrict__ Wf, const float* __restrict__ bias){
    // hoist all A-fragments (snapshot REQUIRED: epilogue overwrites these rows)
    bf16x8_t afr[8];
    #pragma unroll
    for (int kk = 0; kk < 4; ++kk) {
      int kb = kk*64 + lk*16;
      afr[2*kk+0] = *(const bf16x8_t*)((char*)lds_h + r0*256 + (kb ^ swz0));
      afr[2*kk+1] = *(const bf16x8_t*)((char*)lds_h + r1*256 + (kb ^ swz1));
    }
    const short* bp = Wf + lane*8;   // fragment f at bp + f*512 shorts, f = kk*8+ct
    // 4 passes x 2 col-tiles: acc 16 + b 16 regs; depth-2 B pipeline with fences
    #pragma unroll
    for (int p = 0; p < 4; ++p) {
      f32x4_t acc[2][2];
      #pragma unroll
      for (int rt = 0; rt < 2; ++rt)
        #pragma unroll
        for (int c = 0; c < 2; ++c)
          acc[rt][c] = (f32x4_t){0.f,0.f,0.f,0.f};
      bf16x8_t bcur[2], bnext[2];
      #pragma unroll
      for (int c = 0; c < 2; ++c)
        bcur[c] = *(const bf16x8_t*)(bp + (2*p + c)*512);
      #pragma unroll
      for (int kk = 0; kk < 4; ++kk) {
        if (kk < 3) {
          #pragma unroll
          for (int c = 0; c < 2; ++c)
            bnext[c] = *(const bf16x8_t*)(bp + ((kk+1)*8 + 2*p + c)*512);
        }
        #pragma unroll
        for (int c = 0; c < 2; ++c) {
          acc[0][c] = __builtin_amdgcn_mfma_f32_16x16x32_bf16(afr[2*kk+0], bcur[c], acc[0][c], 0, 0, 0);
          acc[1][c] = __builtin_amdgcn_mfma_f32_16x16x32_bf16(afr[2*kk+1], bcur[c], acc[1][c], 0, 0, 0);
        }
        __builtin_amdgcn_sched_barrier(0);   // fence: no load hoisting past this kk-step
        #pragma unroll
        for (int c = 0; c < 2; ++c) bcur[c] = bnext[c];   // register rename
      }
      // epilogue: bias + tanh -> bf16 back into this wave's rows (afr keeps old A safe)
      #pragma unroll
      for (int c = 0; c < 2; ++c) {
        int j = (2*p + c)*16 + lrow;
        float bj = bias[j];
        #pragma unroll
        for (int rt = 0; rt < 2; ++rt) {
          #pragma unroll
          for (int u = 0; u < 4; ++u) {
            int r = rbase + rt*16 + lk*4 + u;   // D layout: col=lane&15, row=(lane>>4)*4+u
            float v = fast_tanh(acc[rt][c][u] + bj);
            *(__bf16*)((char*)lds_h + r*256 + ((j*2) ^ ((r & 7) << 4))) = (__bf16)v;
          }
        }
      }
      __builtin_amdgcn_sched_barrier(0);   // fence: next pass's loads stay below
    }
  };
  gemm_layer(W2f, b2);
  gemm_layer(W3f, b3);

  // ---- layer 4 (VALU): out = h3 @ W4 + b4; lane does row (lane&31), k-half (lane>>5)
  {
    int m = rbase + l31;
    int kh = lane >> 5;
    int swz = (m & 7) << 4;
    const f32x4_t* W4v = (const f32x4_t*)W4;
    float acc = 0.f;
    #pragma unroll
    for (int c = 0; c < 8; ++c) {
      int kb = kh*128 + c*16;
      bf16x8_t v = *(const bf16x8_t*)((char*)lds_h + m*256 + (kb ^ swz));
      f32x4_t wa = W4v[kh*16 + c*2], wb = W4v[kh*16 + c*2 + 1];
      #pragma unroll
      for (int u = 0; u < 4; ++u) acc += (float)v[u] * wa[u];
      #pragma unroll
      for (int u = 0; u < 4; ++u) acc += (float)v[4+u] * wb[u];
    }
    acc += __shfl_xor(acc, 32);    // combine the two k-halves (same m)
    if (lane < 32) out[pbase + l31] = acc + b4[0];
  }
}

// ---- per-center loss terms + deterministic block partials (no atomics)
__global__ __launch_bounds__(256)
void lap_reduce_kernel(const int* __restrict__ cidx, const float* __restrict__ DATAF,
                       const float* __restrict__ LAPLF, const float* __restrict__ mlp,
                       float* __restrict__ partials)
{
  int b = blockIdx.x * 256 + threadIdx.x;   // exactly Bc threads
  int i = cidx[b];
  int ix = i >> 14, iy = (i >> 7) & 127, iz = i & 127;
  bool interior = (ix >= 1) && (ix < 127) && (iy >= 1) && (iy < 127) && (iz >= 1) && (iz < 127);
  float e = fabsf(mlp[b] - DATAF[i]);
  const f32x4_t* ps4 = (const f32x4_t*)(mlp + Bc   + 8*(size_t)b);
  const f32x4_t* pn4 = (const f32x4_t*)(mlp + 9*Bc + 8*(size_t)b);
  f32x4_t psa = ps4[0], psb = ps4[1], pna = pn4[0], pnb = pn4[1];
  auto term = [](float a, float bq, float c, float d){
    return fabsf(a + bq - c - d) / ((a + bq + c + d) * 1.5f);
  };
  float lap = term(pnb[3], pna[0], psb[3], psa[0])    // pn7,pn0,ps7,ps0
            + term(pna[3], pnb[0], psa[3], psb[0])    // pn3,pn4,ps3,ps4
            + term(pnb[1], pna[2], psb[1], psa[2]);   // pn5,pn2,ps5,ps2
  float dl = LAPLF[i] - lap;
  float sq = interior ? dl*dl : 0.f;
  float cn = interior ? 1.f : 0.f;
  #pragma unroll
  for (int o = 32; o > 0; o >>= 1) {
    e  += __shfl_down(e, o);
    sq += __shfl_down(sq, o);
    cn += __shfl_down(cn, o);
  }
  __shared__ float sm[4][3];
  int w = threadIdx.x >> 6;
  if ((threadIdx.x & 63) == 0) { sm[w][0]=e; sm[w][1]=sq; sm[w][2]=cn; }
  __syncthreads();
  if (threadIdx.x == 0) {
    float se=0, ss=0, sc=0;
    #pragma unroll
    for (int k = 0; k < 4; ++k){ se+=sm[k][0]; ss+=sm[k][1]; sc+=sm[k][2]; }
    partials[blockIdx.x*4+0]=se; partials[blockIdx.x*4+1]=ss; partials[blockIdx.x*4+2]=sc;
  }
}

__global__ void lap_finalize_kernel(const float* __restrict__ partials, float* __restrict__ out){
  int l = threadIdx.x;   // 64 threads
  float se=0, ss=0, sc=0;
  for (int r = l; r < 128; r += 64) {
    se += partials[4*r+0]; ss += partials[4*r+1]; sc += partials[4*r+2];
  }
  #pragma unroll
  for (int o = 32; o > 0; o >>= 1) {
    se += __shfl_down(se, o); ss += __shfl_down(ss, o); sc += __shfl_down(sc, o);
  }
  if (l == 0) out[0] = se * (1.0f/32768.f) + ss / fmaxf(sc, 1.f);
}

extern "C" void kernel_launch(void* const* d_in, const int* in_sizes, int n_in,
                              void* d_out, int out_size, void* d_ws, size_t ws_size,
                              hipStream_t stream)
{
  const float* DATAX = (const float*)d_in[0];
  const float* DATAF = (const float*)d_in[1];
  const float* STAGX = (const float*)d_in[2];
  const float* LAPLF = (const float*)d_in[3];
  const float* W1    = (const float*)d_in[4];
  const float* b1    = (const float*)d_in[5];
  const float* W2    = (const float*)d_in[6];
  const float* b2    = (const float*)d_in[7];
  const float* W3    = (const float*)d_in[8];
  const float* b3    = (const float*)d_in[9];
  const float* W4    = (const float*)d_in[10];
  const float* b4    = (const float*)d_in[11];
  const int*   cidx  = (const int*)d_in[12];
  float* out = (float*)d_out;

  char* ws = (char*)d_ws;
  float* partials = (float*)ws;                 // 128*4 floats
  short* W2f      = (short*)(ws + 4096);        // 32 KB
  short* W3f      = (short*)(ws + 36864);       // 32 KB
  float* mlp_out  = (float*)(ws + 69632);       // 557056 floats (~2.2 MB)

  lap_convert_w<<<128, 256, 0, stream>>>(W2, W3, W2f, W3f);
  lap_mlp_kernel<<<P_TOTAL/128, 256, 0, stream>>>(DATAX, STAGX, cidx,
                                                  W1, b1, b2, b3, W4, b4,
                                                  W2f, W3f, mlp_out);
  lap_reduce_kernel<<<Bc/256, 256, 0, stream>>>(cidx, DATAF, LAPLF, mlp_out, partials);
  lap_finalize_kernel<<<1, 64, 0, stream>>>(partials, out);
}

// Round 10
// 109.474 us; speedup vs baseline: 2.7943x; 1.0523x over previous
//
#include <hip/hip_runtime.h>
#include <stdint.h>

#define Bc 32768
#define NSTAG 2048383
#define NFULL 2097152
#define P_TOTAL (17*Bc)   // 557056 = 4352 * 128

typedef short  short8_t __attribute__((ext_vector_type(8)));
typedef __bf16 bf16x8_t __attribute__((ext_vector_type(8)));
typedef __bf16 bf16x4_t __attribute__((ext_vector_type(4)));
typedef float  f32x4_t  __attribute__((ext_vector_type(4)));

#if __has_builtin(__builtin_amdgcn_exp2f)
#define EXP2F(x) __builtin_amdgcn_exp2f(x)
#else
#define EXP2F(x) exp2f(x)
#endif
#if __has_builtin(__builtin_amdgcn_rcpf)
#define RCPF(x) __builtin_amdgcn_rcpf(x)
#else
#define RCPF(x) (1.0f/(x))
#endif

// tanh(x) = 1 - 2/(e^{2x}+1); e^{2x} = 2^(x*2*log2 e). 5 insts, exact at +-inf.
__device__ __forceinline__ float fast_tanh(float x){
  float e = EXP2F(x * 2.885390081777927f);
  return fmaf(-2.0f, RCPF(e + 1.0f), 1.0f);
}

__device__ __forceinline__ short f2bf(float f){
  union { float f; unsigned u; } v; v.f = f;
  unsigned r = v.u + 0x7FFFu + ((v.u >> 16) & 1u);   // RNE
  return (short)(r >> 16);
}

// ---- weight convert to FRAGMENT-MAJOR bf16 layout (A-operand mapping):
// Wf[((kk*8+ct)*64 + lane)*8 + u] = bf16(W[k][j]),  j = ct*16+(lane&15),
// k = kk*32+(lane>>4)*8+u.  B-loads become base + lane*16B + small imm.
__global__ void lap_convert_w(const float* __restrict__ W2, const float* __restrict__ W3,
                              short* __restrict__ W2f, short* __restrict__ W3f){
  int o = blockIdx.x * 256 + threadIdx.x;      // 0..32767
  int which = o >> 14; int e = o & 16383;
  int u = e & 7, lane = (e >> 3) & 63, ct = (e >> 9) & 7, kk = e >> 12;
  int j = ct*16 + (lane & 15);
  int k = kk*32 + (lane >> 4)*8 + u;
  const float* W = which ? W3 : W2;
  short* O = which ? W3f : W2f;
  O[e] = f2bf(W[k*128 + j]);
}

// ---- main MLP kernel: 128 points per block, 32 per wave, fully wave-private.
// r10: operand-swapped MFMA (D = Wf x h^T): lane owns 4 CONSECUTIVE columns of
// one h-row -> packed 8B epilogue writes (16 b64 vs 64 b16 per layer).
// MFMA-class regs: afr32 + acc8 + b4+b4 = 48; r9 demand 142-16 = 126 <= 128.
__global__ __launch_bounds__(256, 4)
void lap_mlp_kernel(const float* __restrict__ DATAX, const float* __restrict__ STAGX,
                    const int* __restrict__ cidx,
                    const float* __restrict__ W1, const float* __restrict__ b1,
                    const float* __restrict__ b2, const float* __restrict__ b3,
                    const float* __restrict__ W4, const float* __restrict__ b4,
                    const short* __restrict__ W2f, const short* __restrict__ W3f,
                    float* __restrict__ out)
{
  __shared__ short lds_h[128*128];   // 32 KB activations; rows XOR-swizzled (256B stride)
  const int t    = threadIdx.x;
  const int lane = t & 63;
  const int wv   = t >> 6;
  const int rbase = wv * 32;                    // this wave's private 32 rows
  const int pbase = blockIdx.x * 128 + rbase;   // this wave's 32 points
  const int l31 = lane & 31;

  // ---- gather: each lane loads coords for row (lane&31); 2 lanes/row redundant (L1-merged)
  float x0, x1, x2;
  {
    int p = pbase + l31;
    const float* sp;
    if (p < Bc) {
      sp = DATAX + 3*(size_t)cidx[p];
    } else {
      int q = p - Bc;
      int isNeig = (q >= 8*Bc) ? 1 : 0;
      if (isNeig) q -= 8*Bc;
      int b = q >> 3, s5 = q & 7;
      int i = cidx[b];
      int ix = i >> 14, iy = (i >> 7) & 127, iz = i & 127;
      int bx = (s5 >> 2) & 1, by = (s5 >> 1) & 1, bz = s5 & 1;
      int dx, dy, dz, hi;
      if (isNeig) { dx = 2*bx-1; dy = 2*by-1; dz = 2*bz-1; hi = NFULL-1; }
      else        { dx = bx-1;   dy = by-1;   dz = bz-1;   hi = NSTAG-1; }
      // reference uses reduced-grid strides (127*127, 127) for BOTH gathers
      int f = (ix+dx)*16129 + (iy+dy)*127 + (iz+dz);
      f = f < 0 ? 0 : (f > hi ? hi : f);
      sp = (isNeig ? DATAX : STAGX) + 3*(size_t)f;
    }
    x0 = sp[0]; x1 = sp[1]; x2 = sp[2];
  }

  // ---- layer 1 (VALU): h1 = tanh(x @ W1 + b1); lane handles row (lane&31), j-half (lane>>5)
  {
    int m = rbase + l31;
    int jh = lane >> 5;
    int swz = (m & 7) << 4;
    char* rowp = (char*)lds_h + m*256;
    const f32x4_t* W1v = (const f32x4_t*)W1;   // [3][32] of float4
    const f32x4_t* b1v = (const f32x4_t*)b1;
    #pragma unroll
    for (int c8 = 0; c8 < 8; ++c8) {
      int j0 = jh*64 + c8*8;
      int q = j0 >> 2;
      f32x4_t bb[2] = { b1v[q],    b1v[q+1] };
      f32x4_t w0[2] = { W1v[q],    W1v[q+1] };
      f32x4_t w1[2] = { W1v[32+q], W1v[32+q+1] };
      f32x4_t w2[2] = { W1v[64+q], W1v[64+q+1] };
      bf16x8_t hv;
      #pragma unroll
      for (int u = 0; u < 8; ++u) {
        int h4 = u >> 2, e4 = u & 3;
        float a = bb[h4][e4] + x0*w0[h4][e4] + x1*w1[h4][e4] + x2*w2[h4][e4];
        hv[u] = (__bf16)fast_tanh(a);
      }
      *(bf16x8_t*)(rowp + ((j0*2) ^ swz)) = hv;   // b128 write
    }
  }
  // no barrier: per-wave DS ops are processed in order; reads below see this wave's writes

  // ---- layers 2,3 (MFMA, operand-swapped); Wf from global (L1-resident 32KB)
  const int lrow = lane & 15, lk = lane >> 4;
  const int r0 = rbase + lrow, r1 = r0 + 16;
  const int swz0 = (r0 & 7) << 4, swz1 = (r1 & 7) << 4;
  auto gemm_layer = [&](const short* __restrict__ Wf, const float* __restrict__ bias){
    // hoist all A..B-fragments of h (snapshot REQUIRED: epilogue overwrites rows)
    bf16x8_t afr[8];
    #pragma unroll
    for (int kk = 0; kk < 4; ++kk) {
      int kb = kk*64 + lk*16;
      afr[2*kk+0] = *(const bf16x8_t*)((char*)lds_h + r0*256 + (kb ^ swz0));
      afr[2*kk+1] = *(const bf16x8_t*)((char*)lds_h + r1*256 + (kb ^ swz1));
    }
    const short* bp = Wf + lane*8;   // fragment f = kk*8+ct at bp + f*512 shorts
    // 8 passes x 1 col-tile: acc 8 + b 8 regs; depth-2 W pipeline with fences
    #pragma unroll
    for (int ct = 0; ct < 8; ++ct) {
      f32x4_t acc0 = (f32x4_t){0.f,0.f,0.f,0.f};
      f32x4_t acc1 = (f32x4_t){0.f,0.f,0.f,0.f};
      bf16x8_t bcur = *(const bf16x8_t*)(bp + ct*512);
      bf16x8_t bnext = bcur;
      #pragma unroll
      for (int kk = 0; kk < 4; ++kk) {
        if (kk < 3) bnext = *(const bf16x8_t*)(bp + ((kk+1)*8 + ct)*512);
        // D = Wf x h^T: D col(lane&15) = h-row m, D row(lk*4+u) = out col j
        acc0 = __builtin_amdgcn_mfma_f32_16x16x32_bf16(bcur, afr[2*kk+0], acc0, 0, 0, 0);
        acc1 = __builtin_amdgcn_mfma_f32_16x16x32_bf16(bcur, afr[2*kk+1], acc1, 0, 0, 0);
        __builtin_amdgcn_sched_barrier(0);   // fence: no load hoisting past this kk-step
        bcur = bnext;
      }
      // epilogue: bias + tanh -> 4 packed bf16 = one 8B write per rt
      f32x4_t bv = ((const f32x4_t*)bias)[ct*4 + lk];   // bias[j], j=ct*16+lk*4+u
      {
        bf16x4_t hv;
        #pragma unroll
        for (int u = 0; u < 4; ++u) hv[u] = (__bf16)fast_tanh(acc0[u] + bv[u]);
        *(bf16x4_t*)((char*)lds_h + r0*256 + ((ct*32 + lk*8) ^ swz0)) = hv;
      }
      {
        bf16x4_t hv;
        #pragma unroll
        for (int u = 0; u < 4; ++u) hv[u] = (__bf16)fast_tanh(acc1[u] + bv[u]);
        *(bf16x4_t*)((char*)lds_h + r1*256 + ((ct*32 + lk*8) ^ swz1)) = hv;
      }
      __builtin_amdgcn_sched_barrier(0);   // fence: next pass's loads stay below
    }
  };
  gemm_layer(W2f, b2);
  gemm_layer(W3f, b3);

  // ---- layer 4 (VALU): out = h3 @ W4 + b4; lane does row (lane&31), k-half (lane>>5)
  {
    int m = rbase + l31;
    int kh = lane >> 5;
    int swz = (m & 7) << 4;
    const f32x4_t* W4v = (const f32x4_t*)W4;
    float acc = 0.f;
    #pragma unroll
    for (int c = 0; c < 8; ++c) {
      int kb = kh*128 + c*16;
      bf16x8_t v = *(const bf16x8_t*)((char*)lds_h + m*256 + (kb ^ swz));
      f32x4_t wa = W4v[kh*16 + c*2], wb = W4v[kh*16 + c*2 + 1];
      #pragma unroll
      for (int u = 0; u < 4; ++u) acc += (float)v[u] * wa[u];
      #pragma unroll
      for (int u = 0; u < 4; ++u) acc += (float)v[4+u] * wb[u];
    }
    acc += __shfl_xor(acc, 32);    // combine the two k-halves (same m)
    if (lane < 32) out[pbase + l31] = acc + b4[0];
  }
}

// ---- per-center loss terms + deterministic block partials (no atomics)
__global__ __launch_bounds__(256)
void lap_reduce_kernel(const int* __restrict__ cidx, const float* __restrict__ DATAF,
                       const float* __restrict__ LAPLF, const float* __restrict__ mlp,
                       float* __restrict__ partials)
{
  int b = blockIdx.x * 256 + threadIdx.x;   // exactly Bc threads
  int i = cidx[b];
  int ix = i >> 14, iy = (i >> 7) & 127, iz = i & 127;
  bool interior = (ix >= 1) && (ix < 127) && (iy >= 1) && (iy < 127) && (iz >= 1) && (iz < 127);
  float e = fabsf(mlp[b] - DATAF[i]);
  const f32x4_t* ps4 = (const f32x4_t*)(mlp + Bc   + 8*(size_t)b);
  const f32x4_t* pn4 = (const f32x4_t*)(mlp + 9*Bc + 8*(size_t)b);
  f32x4_t psa = ps4[0], psb = ps4[1], pna = pn4[0], pnb = pn4[1];
  auto term = [](float a, float bq, float c, float d){
    return fabsf(a + bq - c - d) / ((a + bq + c + d) * 1.5f);
  };
  float lap = term(pnb[3], pna[0], psb[3], psa[0])    // pn7,pn0,ps7,ps0
            + term(pna[3], pnb[0], psa[3], psb[0])    // pn3,pn4,ps3,ps4
            + term(pnb[1], pna[2], psb[1], psa[2]);   // pn5,pn2,ps5,ps2
  float dl = LAPLF[i] - lap;
  float sq = interior ? dl*dl : 0.f;
  float cn = interior ? 1.f : 0.f;
  #pragma unroll
  for (int o = 32; o > 0; o >>= 1) {
    e  += __shfl_down(e, o);
    sq += __shfl_down(sq, o);
    cn += __shfl_down(cn, o);
  }
  __shared__ float sm[4][3];
  int w = threadIdx.x >> 6;
  if ((threadIdx.x & 63) == 0) { sm[w][0]=e; sm[w][1]=sq; sm[w][2]=cn; }
  __syncthreads();
  if (threadIdx.x == 0) {
    float se=0, ss=0, sc=0;
    #pragma unroll
    for (int k = 0; k < 4; ++k){ se+=sm[k][0]; ss+=sm[k][1]; sc+=sm[k][2]; }
    partials[blockIdx.x*4+0]=se; partials[blockIdx.x*4+1]=ss; partials[blockIdx.x*4+2]=sc;
  }
}

__global__ void lap_finalize_kernel(const float* __restrict__ partials, float* __restrict__ out){
  int l = threadIdx.x;   // 64 threads
  float se=0, ss=0, sc=0;
  for (int r = l; r < 128; r += 64) {
    se += partials[4*r+0]; ss += partials[4*r+1]; sc += partials[4*r+2];
  }
  #pragma unroll
  for (int o = 32; o > 0; o >>= 1) {
    se += __shfl_down(se, o); ss += __shfl_down(ss, o); sc += __shfl_down(sc, o);
  }
  if (l == 0) out[0] = se * (1.0f/32768.f) + ss / fmaxf(sc, 1.f);
}

extern "C" void kernel_launch(void* const* d_in, const int* in_sizes, int n_in,
                              void* d_out, int out_size, void* d_ws, size_t ws_size,
                              hipStream_t stream)
{
  const float* DATAX = (const float*)d_in[0];
  const float* DATAF = (const float*)d_in[1];
  const float* STAGX = (const float*)d_in[2];
  const float* LAPLF = (const float*)d_in[3];
  const float* W1    = (const float*)d_in[4];
  const float* b1    = (const float*)d_in[5];
  const float* W2    = (const float*)d_in[6];
  const float* b2    = (const float*)d_in[7];
  const float* W3    = (const float*)d_in[8];
  const float* b3    = (const float*)d_in[9];
  const float* W4    = (const float*)d_in[10];
  const float* b4    = (const float*)d_in[11];
  const int*   cidx  = (const int*)d_in[12];
  float* out = (float*)d_out;

  char* ws = (char*)d_ws;
  float* partials = (float*)ws;                 // 128*4 floats
  short* W2f      = (short*)(ws + 4096);        // 32 KB
  short* W3f      = (short*)(ws + 36864);       // 32 KB
  float* mlp_out  = (float*)(ws + 69632);       // 557056 floats (~2.2 MB)

  lap_convert_w<<<128, 256, 0, stream>>>(W2, W3, W2f, W3f);
  lap_mlp_kernel<<<P_TOTAL/128, 256, 0, stream>>>(DATAX, STAGX, cidx,
                                                  W1, b1, b2, b3, W4, b4,
                                                  W2f, W3f, mlp_out);
  lap_reduce_kernel<<<Bc/256, 256, 0, stream>>>(cidx, DATAF, LAPLF, mlp_out, partials);
  lap_finalize_kernel<<<1, 64, 0, stream>>>(partials, out);
}